// Round 1
// baseline (501.662 us; speedup 1.0000x reference)
//
#include <hip/hip_runtime.h>
#include <hip/hip_bf16.h>
#include <math.h>

// B=16, F=4096, Q=64, DIM=512, H=8, DH=64, MULT=2
typedef short bf16x8 __attribute__((ext_vector_type(8)));
typedef float f32x4 __attribute__((ext_vector_type(4)));

__device__ __forceinline__ f32x4 mfma16(bf16x8 a, bf16x8 b, f32x4 c) {
    return __builtin_amdgcn_mfma_f32_16x16x32_bf16(a, b, c, 0, 0, 0);
}

// manual fp32 -> bf16 round-to-nearest-even (all values finite here)
__device__ __forceinline__ unsigned short f2b(float f) {
    unsigned int x = __float_as_uint(f);
    unsigned int r = (x + 0x7fffu + ((x >> 16) & 1u)) >> 16;
    return (unsigned short)r;
}

#define GLOBAL_AS(p) ((__attribute__((address_space(1))) void*)(p))
#define LDS_AS(p)    ((__attribute__((address_space(3))) void*)(p))

// ---------------- LayerNorm: one wave per 512-elem row, fp32 in -> bf16 out --------
__global__ __launch_bounds__(256) void ln_rows(const float* __restrict__ in,
                                               const float* __restrict__ gw,
                                               const float* __restrict__ bw,
                                               unsigned short* __restrict__ out) {
    int row = blockIdx.x * 4 + (threadIdx.x >> 6);
    int lane = threadIdx.x & 63;
    const float* rp = in + (size_t)row * 512;
    float4 x0 = *(const float4*)(rp + lane * 4);
    float4 x1 = *(const float4*)(rp + 256 + lane * 4);
    float s  = x0.x + x0.y + x0.z + x0.w + x1.x + x1.y + x1.z + x1.w;
    float sq = x0.x*x0.x + x0.y*x0.y + x0.z*x0.z + x0.w*x0.w
             + x1.x*x1.x + x1.y*x1.y + x1.z*x1.z + x1.w*x1.w;
#pragma unroll
    for (int m = 1; m < 64; m <<= 1) {
        s  += __shfl_xor(s, m);
        sq += __shfl_xor(sq, m);
    }
    float mean = s * (1.0f / 512.0f);
    float var  = sq * (1.0f / 512.0f) - mean * mean;
    float rs   = rsqrtf(var + 1e-5f);
    float4 g0 = *(const float4*)(gw + lane * 4);
    float4 g1 = *(const float4*)(gw + 256 + lane * 4);
    float4 b0 = *(const float4*)(bw + lane * 4);
    float4 b1 = *(const float4*)(bw + 256 + lane * 4);
    ushort4 o0, o1;
    o0.x = f2b((x0.x - mean) * rs * g0.x + b0.x);
    o0.y = f2b((x0.y - mean) * rs * g0.y + b0.y);
    o0.z = f2b((x0.z - mean) * rs * g0.z + b0.z);
    o0.w = f2b((x0.w - mean) * rs * g0.w + b0.w);
    o1.x = f2b((x1.x - mean) * rs * g1.x + b1.x);
    o1.y = f2b((x1.y - mean) * rs * g1.y + b1.y);
    o1.z = f2b((x1.z - mean) * rs * g1.z + b1.z);
    o1.w = f2b((x1.w - mean) * rs * g1.w + b1.w);
    *(ushort4*)(out + (size_t)row * 512 + lane * 4) = o0;
    *(ushort4*)(out + (size_t)row * 512 + 256 + lane * 4) = o1;
}

// ---------------- weight transpose + fp32->bf16: out[C,R] = bf16(in[R,C]^T) --------
__global__ __launch_bounds__(256) void transpose_bf16(const float* __restrict__ in,
                                                      unsigned short* __restrict__ out,
                                                      int R, int C) {
    __shared__ float tile[32][33];
    int tx = threadIdx.x & 31, ty = threadIdx.x >> 5;
    int c0 = blockIdx.x * 32, r0 = blockIdx.y * 32;
#pragma unroll
    for (int i = 0; i < 32; i += 8)
        tile[ty + i][tx] = in[(size_t)(r0 + ty + i) * C + c0 + tx];
    __syncthreads();
#pragma unroll
    for (int i = 0; i < 32; i += 8)
        out[(size_t)(c0 + ty + i) * R + r0 + tx] = f2b(tile[tx][ty + i]);
}

// ---------------- GEMM: C[M,N] = A[M,K] * Bt[N,K]^T  (all bf16, fp32 accum) --------
// 128x128 tile, BK=32, 4 waves each 64x64. EPI: 0=store bf16, 1=relu+bf16, 2=store f32
template <int EPI>
__global__ __launch_bounds__(256) void gemm_bt(const unsigned short* __restrict__ A,
                                               const unsigned short* __restrict__ Bt,
                                               void* __restrict__ Cv,
                                               int M, int N, int K) {
    __shared__ unsigned short As[128 * 32];
    __shared__ unsigned short Bs[128 * 32];
    const int tid = threadIdx.x;
    const int wave = tid >> 6, lane = tid & 63;
    const int qd = lane >> 4, cc = lane & 15;
    const int m0 = blockIdx.y * 128, n0 = blockIdx.x * 128;
    const int wm = (wave >> 1) * 64, wn = (wave & 1) * 64;
    const int lrow = lane >> 2;        // 0..15 within a 16-row slab
    const int lcol = (lane & 3) * 8;   // element offset in k
    f32x4 acc[4][4] = {};

    for (int kt = 0; kt < K; kt += 32) {
#pragma unroll
        for (int r = 0; r < 2; ++r) {
            int slab = wave * 16 + r * 64;
            const unsigned short* ga = A + (size_t)(m0 + slab + lrow) * K + kt + lcol;
            __builtin_amdgcn_global_load_lds(GLOBAL_AS(ga), LDS_AS(&As[slab * 32]), 16, 0, 0);
            const unsigned short* gb = Bt + (size_t)(n0 + slab + lrow) * K + kt + lcol;
            __builtin_amdgcn_global_load_lds(GLOBAL_AS(gb), LDS_AS(&Bs[slab * 32]), 16, 0, 0);
        }
        __syncthreads();
        bf16x8 af[4], bfr[4];
#pragma unroll
        for (int i = 0; i < 4; ++i)
            af[i] = *(const bf16x8*)&As[(wm + i * 16 + cc) * 32 + qd * 8];
#pragma unroll
        for (int j = 0; j < 4; ++j)
            bfr[j] = *(const bf16x8*)&Bs[(wn + j * 16 + cc) * 32 + qd * 8];
#pragma unroll
        for (int i = 0; i < 4; ++i)
#pragma unroll
            for (int j = 0; j < 4; ++j)
                acc[i][j] = mfma16(af[i], bfr[j], acc[i][j]);
        __syncthreads();
    }
    // epilogue: C/D layout col=lane&15, row=quad*4+reg
#pragma unroll
    for (int i = 0; i < 4; ++i) {
#pragma unroll
        for (int j = 0; j < 4; ++j) {
            int row = m0 + wm + i * 16 + qd * 4;
            int col = n0 + wn + j * 16 + cc;
#pragma unroll
            for (int r = 0; r < 4; ++r) {
                float v = acc[i][j][r];
                if (EPI == 1) v = fmaxf(v, 0.0f);
                if (EPI == 2)
                    ((float*)Cv)[(size_t)(row + r) * N + col] = v;
                else
                    ((unsigned short*)Cv)[(size_t)(row + r) * N + col] = f2b(v);
            }
        }
    }
}

// ---------------- fused masked flash attention ----------------
// grid = 512 blocks: (b, h, q-tile of 16). 4 waves split F=4096 into 1024-chunks,
// online softmax per wave, cross-wave combine in LDS.
// Qb: (B*Q, 512) bf16 ; Kb: (B*F, 512) bf16 ; VT: (512, B*F) bf16 ; out fp32 (B*Q,512)
__global__ __launch_bounds__(256) void attn_kernel(const unsigned short* __restrict__ Qb,
                                                   const unsigned short* __restrict__ Kb,
                                                   const unsigned short* __restrict__ VT,
                                                   const int* __restrict__ mask,
                                                   float* __restrict__ outp) {
    int blk = blockIdx.x;
    int b = blk >> 5;
    int h = (blk >> 2) & 7;
    int qt = blk & 3;
    int wave = threadIdx.x >> 6, lane = threadIdx.x & 63;
    int qd = lane >> 4, cc = lane & 15;

    __shared__ float O_lds[16][64];
    __shared__ float m_lds[4][16];
    __shared__ float l_lds[4][16];
    __shared__ float lt_lds[16];
    __shared__ unsigned short p_lds[4][16][72];  // stride 72 -> 16B aligned rows

    for (int i = threadIdx.x; i < 16 * 64; i += 256)
        ((float*)O_lds)[i] = 0.0f;

    const unsigned short* qrow = Qb + (size_t)(b * 64 + qt * 16 + cc) * 512 + h * 64;
    bf16x8 qf0 = *(const bf16x8*)(qrow + qd * 8);
    bf16x8 qf1 = *(const bf16x8*)(qrow + 32 + qd * 8);

    const unsigned short* Kbase = Kb + (size_t)b * 4096 * 512 + h * 64;
    const unsigned short* Vbase = VT + (size_t)(h * 64) * 65536 + (size_t)b * 4096;
    const int* mbase = mask + b * 4096;

    float mrow[4], lrow[4];
    f32x4 O4[4] = {};
#pragma unroll
    for (int r = 0; r < 4; ++r) { mrow[r] = -INFINITY; lrow[r] = 0.0f; }

    for (int it = 0; it < 16; ++it) {
        int f0 = wave * 1024 + it * 64;
        f32x4 s4[4] = {};
#pragma unroll
        for (int t = 0; t < 4; ++t) {
            const unsigned short* kr = Kbase + (size_t)(f0 + t * 16 + cc) * 512;
            bf16x8 k0 = *(const bf16x8*)(kr + qd * 8);
            bf16x8 k1 = *(const bf16x8*)(kr + 32 + qd * 8);
            s4[t] = mfma16(qf0, k0, s4[t]);
            s4[t] = mfma16(qf1, k1, s4[t]);
        }
        int mv[4];
#pragma unroll
        for (int t = 0; t < 4; ++t) mv[t] = mbase[f0 + t * 16 + cc];

        float pbuf[4][4];
        float tmax[4];
#pragma unroll
        for (int r = 0; r < 4; ++r) tmax[r] = -INFINITY;
#pragma unroll
        for (int t = 0; t < 4; ++t)
#pragma unroll
            for (int r = 0; r < 4; ++r) {
                float v = mv[t] ? s4[t][r] * 0.125f : -INFINITY;
                pbuf[t][r] = v;
                tmax[r] = fmaxf(tmax[r], v);
            }
#pragma unroll
        for (int r = 0; r < 4; ++r) {
#pragma unroll
            for (int mm = 1; mm < 16; mm <<= 1)
                tmax[r] = fmaxf(tmax[r], __shfl_xor(tmax[r], mm));
        }
        float rsum[4];
#pragma unroll
        for (int r = 0; r < 4; ++r) {
            float mnew = fmaxf(mrow[r], tmax[r]);
            float alpha = (mrow[r] == -INFINITY) ? 0.0f : __expf(mrow[r] - mnew);
            float rs = 0.0f;
#pragma unroll
            for (int t = 0; t < 4; ++t) {
                float pv = mv[t] ? __expf(pbuf[t][r] - mnew) : 0.0f;
                pbuf[t][r] = pv;
                rs += pv;
            }
            rsum[r] = rs;
            lrow[r] *= alpha;
            mrow[r] = mnew;
#pragma unroll
            for (int g = 0; g < 4; ++g) O4[g][r] *= alpha;
        }
#pragma unroll
        for (int r = 0; r < 4; ++r) {
            float rs = rsum[r];
#pragma unroll
            for (int mm = 1; mm < 16; mm <<= 1) rs += __shfl_xor(rs, mm);
            lrow[r] += rs;
        }
        // P: C-layout -> LDS -> A-fragment (per-wave private buffer, no barrier)
#pragma unroll
        for (int t = 0; t < 4; ++t)
#pragma unroll
            for (int r = 0; r < 4; ++r)
                p_lds[wave][qd * 4 + r][t * 16 + cc] = f2b(pbuf[t][r]);
        bf16x8 pf0 = *(const bf16x8*)&p_lds[wave][cc][qd * 8];
        bf16x8 pf1 = *(const bf16x8*)&p_lds[wave][cc][32 + qd * 8];
#pragma unroll
        for (int g = 0; g < 4; ++g) {
            const unsigned short* vr = Vbase + (size_t)(g * 16 + cc) * 65536 + f0;
            bf16x8 v0 = *(const bf16x8*)(vr + qd * 8);
            bf16x8 v1 = *(const bf16x8*)(vr + 32 + qd * 8);
            O4[g] = mfma16(pf0, v0, O4[g]);
            O4[g] = mfma16(pf1, v1, O4[g]);
        }
    }
    // cross-wave combine
    if (cc == 0) {
#pragma unroll
        for (int r = 0; r < 4; ++r) {
            m_lds[wave][qd * 4 + r] = mrow[r];
            l_lds[wave][qd * 4 + r] = lrow[r];
        }
    }
    __syncthreads();
#pragma unroll
    for (int r = 0; r < 4; ++r) {
        int q = qd * 4 + r;
        float mt = fmaxf(fmaxf(m_lds[0][q], m_lds[1][q]), fmaxf(m_lds[2][q], m_lds[3][q]));
        float ls = 0.0f;
#pragma unroll
        for (int w = 0; w < 4; ++w) {
            float mw = m_lds[w][q];
            if (mw != -INFINITY) ls += __expf(mw - mt) * l_lds[w][q];
        }
        float coef = (mrow[r] == -INFINITY) ? 0.0f : __expf(mrow[r] - mt);
#pragma unroll
        for (int g = 0; g < 4; ++g) O4[g][r] *= coef;
        if (wave == 0 && cc == 0) lt_lds[q] = ls;
    }
#pragma unroll
    for (int g = 0; g < 4; ++g)
#pragma unroll
        for (int r = 0; r < 4; ++r)
            atomicAdd(&O_lds[qd * 4 + r][g * 16 + cc], O4[g][r]);
    __syncthreads();
    for (int i = threadIdx.x; i < 1024; i += 256) {
        int q = i >> 6, d = i & 63;
        float l = lt_lds[q];
        float val = (l > 0.0f) ? O_lds[q][d] / l : 0.0f;
        outp[(size_t)(b * 64 + qt * 16 + q) * 512 + h * 64 + d] = val;
    }
}

// ---------------- host ----------------
extern "C" void kernel_launch(void* const* d_in, const int* in_sizes, int n_in,
                              void* d_out, int out_size, void* d_ws, size_t ws_size,
                              hipStream_t stream) {
    const float* features = (const float*)d_in[0];
    const float* latents  = (const float*)d_in[1];
    const int*   mask     = (const int*)d_in[2];
    const float* gf  = (const float*)d_in[3];
    const float* bf_ = (const float*)d_in[4];
    const float* gl  = (const float*)d_in[5];
    const float* bl  = (const float*)d_in[6];
    const float* Wq  = (const float*)d_in[7];
    const float* Wk  = (const float*)d_in[8];
    const float* Wv  = (const float*)d_in[9];
    const float* gff = (const float*)d_in[10];
    const float* bff = (const float*)d_in[11];
    const float* W1  = (const float*)d_in[12];
    const float* W2  = (const float*)d_in[13];

    char* ws = (char*)d_ws;
    unsigned short* xn   = (unsigned short*)(ws);                    // 64 MB (65536x512)
    unsigned short* Kbuf = (unsigned short*)(ws + 67108864ull);      // 64 MB (65536x512)
    unsigned short* VTb  = (unsigned short*)(ws + 134217728ull);     // 64 MB (512x65536)
    unsigned short* latn = (unsigned short*)(ws + 201326592ull);     // 1 MB
    unsigned short* Qbuf = (unsigned short*)(ws + 202375168ull);     // 1 MB
    float*          atto = (float*)(ws + 203423744ull);              // 2 MB fp32
    unsigned short* ffin = (unsigned short*)(ws + 205520896ull);     // 1 MB
    unsigned short* hbuf = (unsigned short*)(ws + 206569472ull);     // 2 MB
    unsigned short* WqT  = (unsigned short*)(ws + 208666624ull);
    unsigned short* WkT  = (unsigned short*)(ws + 209190912ull);
    unsigned short* WvT  = (unsigned short*)(ws + 209715200ull);
    unsigned short* W1T  = (unsigned short*)(ws + 210239488ull);
    unsigned short* W2T  = (unsigned short*)(ws + 211288064ull);

    // weights -> bf16 transposed (N,K) layouts
    transpose_bf16<<<dim3(16, 16), 256, 0, stream>>>(Wq, WqT, 512, 512);
    transpose_bf16<<<dim3(16, 16), 256, 0, stream>>>(Wk, WkT, 512, 512);
    transpose_bf16<<<dim3(16, 16), 256, 0, stream>>>(Wv, WvT, 512, 512);
    transpose_bf16<<<dim3(32, 16), 256, 0, stream>>>(W1, W1T, 512, 1024);
    transpose_bf16<<<dim3(16, 32), 256, 0, stream>>>(W2, W2T, 1024, 512);

    // LayerNorms -> bf16
    ln_rows<<<16384, 256, 0, stream>>>(features, gf, bf_, xn);
    ln_rows<<<256, 256, 0, stream>>>(latents, gl, bl, latn);

    // K = xn @ Wk          : (65536,512)
    gemm_bt<0><<<dim3(4, 512), 256, 0, stream>>>(xn, WkT, Kbuf, 65536, 512, 512);
    // V^T = Wv^T @ xn^T    : (512,65536)  (A=WvT, Bt=xn)
    gemm_bt<0><<<dim3(512, 4), 256, 0, stream>>>(WvT, xn, VTb, 512, 65536, 512);
    // Qp = latn @ Wq       : (1024,512)
    gemm_bt<0><<<dim3(4, 8), 256, 0, stream>>>(latn, WqT, Qbuf, 1024, 512, 512);

    // fused masked flash attention -> fp32 (B*Q, 512)
    attn_kernel<<<512, 256, 0, stream>>>(Qbuf, Kbuf, VTb, mask, atto);

    // FF: LN -> W1 -> relu -> W2
    ln_rows<<<256, 256, 0, stream>>>(atto, gff, bff, ffin);
    gemm_bt<1><<<dim3(8, 8), 256, 0, stream>>>(ffin, W1T, hbuf, 1024, 1024, 512);
    gemm_bt<2><<<dim3(4, 8), 256, 0, stream>>>(hbuf, W2T, (float*)d_out, 1024, 512, 1024);
}